// Round 7
// baseline (693.725 us; speedup 1.0000x reference)
//
#include <hip/hip_runtime.h>

#define D 512
#define NTAB 100000   // rows in x / hist0 / hist1

typedef __bf16 bf16x8 __attribute__((ext_vector_type(8)));
typedef float f32x4 __attribute__((ext_vector_type(4)));
typedef int   i32x2 __attribute__((ext_vector_type(2)));

__device__ __forceinline__ unsigned f2bf(float f){
  union { float f; unsigned u; } v; v.f = f;
  unsigned r = v.u + 0x7fffu + ((v.u >> 16) & 1u);
  return r >> 16;
}
__device__ __forceinline__ float bf2f(unsigned h){
  union { unsigned u; float f; } v; v.u = h << 16; return v.f;
}

// ---------------- weights f32 -> bf16 (both tables, one launch) ----------------
__global__ void k_f2bw(const float* __restrict__ w0, const float* __restrict__ w1,
                       unsigned short* __restrict__ o0, unsigned short* __restrict__ o1){
  int i = blockIdx.x*blockDim.x + threadIdx.x;
  if (i < D*D) o0[i] = (unsigned short)f2bf(w0[i]);
  else { i -= D*D; o1[i] = (unsigned short)f2bf(w1[i]); }
}

// ---------------- f32 -> bf16 table convert, x8/thread (NT reads) ----------------
__global__ __launch_bounds__(256) void k_f2b8(const float* __restrict__ in, unsigned short* __restrict__ out, int n8){
  int i = blockIdx.x*256 + threadIdx.x;
  if (i >= n8) return;
  const f32x4* p = (const f32x4*)(in + (size_t)i*8);
  f32x4 v0 = __builtin_nontemporal_load(p);
  f32x4 v1 = __builtin_nontemporal_load(p+1);
  uint4 r;
  r.x = f2bf(v0[0]) | (f2bf(v0[1])<<16);
  r.y = f2bf(v0[2]) | (f2bf(v0[3])<<16);
  r.z = f2bf(v1[0]) | (f2bf(v1[1])<<16);
  r.w = f2bf(v1[2]) | (f2bf(v1[3])<<16);
  *(uint4*)(out + (size_t)i*8) = r;
}

// ---------------- out[row] = bf16(T_f32[idx[row]]) ----------------
__global__ __launch_bounds__(256) void k_gather1_bf16(
    const float* __restrict__ T, const int* __restrict__ idx,
    unsigned short* __restrict__ out, int nrows)
{
  int g = blockIdx.x*256 + threadIdx.x;
  if (g >= (nrows << 7)) return;
  int row = g >> 7, q = (g & 127) << 2;
  int s = idx[row];
  f32x4 v = __builtin_nontemporal_load((const f32x4*)(T + (size_t)s*D + q));
  ushort4 r;
  r.x = (unsigned short)f2bf(v[0]); r.y = (unsigned short)f2bf(v[1]);
  r.z = (unsigned short)f2bf(v[2]); r.w = (unsigned short)f2bf(v[3]);
  *(ushort4*)(out + (size_t)row*D + q) = r;
}

// ---------------- merged CSR build ----------------
// layer0: s0-edge -> 2 entries into cnt0; f0 -> 1. layer1: s1,f1 -> 1 into cnt1.
__global__ void k_count2(const int* __restrict__ s0r, int nS0,
                         const int* __restrict__ f0r, int nF0, int* cnt0,
                         const int* __restrict__ s1r, int nS1,
                         const int* __restrict__ f1r, int nF1, int* cnt1)
{
  int i = blockIdx.x*blockDim.x + threadIdx.x;
  if (i < nS0){ atomicAdd(&cnt0[s0r[i]], 2); return; }
  i -= nS0;
  if (i < nF0){ atomicAdd(&cnt0[f0r[i]], 1); return; }
  i -= nF0;
  if (i < nS1){ atomicAdd(&cnt1[s1r[i]], 1); return; }
  i -= nS1;
  if (i < nF1){ atomicAdd(&cnt1[f1r[i]], 1); }
}

__global__ __launch_bounds__(1024) void k_exscan2(
    const int* c0, int* r0, int n0,
    const int* c1, int* r1, int n1)
{
  __shared__ int part[1024];
  const int* cnt = blockIdx.x ? c1 : c0;
  int* rp        = blockIdx.x ? r1 : r0;
  int n          = blockIdx.x ? n1 : n0;
  int t = threadIdx.x;
  int chunk = n >> 10;
  int base = t*chunk;
  int s = 0;
  for (int i=0;i<chunk;i++) s += cnt[base+i];
  part[t] = s; __syncthreads();
  for (int off=1; off<1024; off<<=1){
    int v = (t>=off) ? part[t-off] : 0;
    __syncthreads();
    part[t] += v;
    __syncthreads();
  }
  int run = (t==0) ? 0 : part[t-1];
  for (int i=0;i<chunk;i++){ rp[base+i] = run; run += cnt[base+i]; }
  if (t == 1023) rp[n] = run;
}

// fill: layer0 s-edges emit (sid0[c], +v) and (NTAB+sid0[c], -v); f0 emits (NTAB+fid0[c], +v)
//       layer1 s-edges emit (N1+c, +v); f1 emits (c, +v)
__global__ void k_fill2(
    const int* __restrict__ s0r, const int* __restrict__ s0c, const float* __restrict__ s0v, int nS0,
    const int* __restrict__ f0r, const int* __restrict__ f0c, const float* __restrict__ f0v, int nF0,
    const int* __restrict__ sid0, const int* __restrict__ fid0,
    const int* __restrict__ rp0, int* __restrict__ fill0, i32x2* __restrict__ bce0,
    const int* __restrict__ s1r, const int* __restrict__ s1c, const float* __restrict__ s1v, int nS1,
    const int* __restrict__ f1r, const int* __restrict__ f1c, const float* __restrict__ f1v, int nF1,
    const int* __restrict__ rp1, int* __restrict__ fill1, i32x2* __restrict__ bce1,
    int N1off)
{
  int i = blockIdx.x*blockDim.x + threadIdx.x;
  if (i < nS0){
    int r = s0r[i];
    int p = atomicAdd(&fill0[r], 2);
    int base = rp0[r] + p;
    int c = sid0[s0c[i]];
    float v = s0v[i];
    i32x2 e0; e0[0] = c;        e0[1] = __float_as_int(v);
    i32x2 e1; e1[0] = NTAB + c; e1[1] = __float_as_int(-v);
    bce0[base]   = e0;
    bce0[base+1] = e1;
    return;
  }
  i -= nS0;
  if (i < nF0){
    int r = f0r[i];
    int p = atomicAdd(&fill0[r], 1);
    i32x2 e; e[0] = NTAB + fid0[f0c[i]]; e[1] = __float_as_int(f0v[i]);
    bce0[rp0[r] + p] = e;
    return;
  }
  i -= nF0;
  if (i < nS1){
    int r = s1r[i];
    int p = atomicAdd(&fill1[r], 1);
    i32x2 e; e[0] = N1off + s1c[i]; e[1] = __float_as_int(s1v[i]);
    bce1[rp1[r] + p] = e;
    return;
  }
  i -= nS1;
  if (i < nF1){
    int r = f1r[i];
    int p = atomicAdd(&fill1[r], 1);
    i32x2 e; e[0] = f1c[i]; e[1] = __float_as_int(f1v[i]);
    bce1[rp1[r] + p] = e;
  }
}

// ---------------- uniform merged SpMM: one WAVE per row, persistent grid ----------------
__device__ __forceinline__ void acc_bf16(float* a, uint4 p, float v){
  a[0] += v*bf2f(p.x & 0xffffu); a[1] += v*bf2f(p.x >> 16);
  a[2] += v*bf2f(p.y & 0xffffu); a[3] += v*bf2f(p.y >> 16);
  a[4] += v*bf2f(p.z & 0xffffu); a[5] += v*bf2f(p.z >> 16);
  a[6] += v*bf2f(p.w & 0xffffu); a[7] += v*bf2f(p.w >> 16);
}

__global__ __launch_bounds__(256) void k_spmm(
    const int* __restrict__ rp, const i32x2* __restrict__ bce,
    const unsigned short* __restrict__ H, unsigned short* __restrict__ out, int nrows)
{
  int wid = threadIdx.x >> 6, lane = threadIdx.x & 63;
  int stride = gridDim.x * 4;
  for (int row = blockIdx.x*4 + wid; row < nrows; row += stride){
    float a[8] = {0.f,0.f,0.f,0.f,0.f,0.f,0.f,0.f};
    int j = rp[row], je = rp[row+1];
    for (; j + 8 <= je; j += 8){
      i32x2 e[8]; uint4 p[8];
      #pragma unroll
      for (int u=0;u<8;u++) e[u] = __builtin_nontemporal_load(bce + j + u);
      #pragma unroll
      for (int u=0;u<8;u++) p[u] = *(const uint4*)(H + (size_t)e[u][0]*D + lane*8);
      #pragma unroll
      for (int u=0;u<8;u++) acc_bf16(a, p[u], __int_as_float(e[u][1]));
    }
    if (j + 4 <= je){
      i32x2 e[4]; uint4 p[4];
      #pragma unroll
      for (int u=0;u<4;u++) e[u] = __builtin_nontemporal_load(bce + j + u);
      #pragma unroll
      for (int u=0;u<4;u++) p[u] = *(const uint4*)(H + (size_t)e[u][0]*D + lane*8);
      #pragma unroll
      for (int u=0;u<4;u++) acc_bf16(a, p[u], __int_as_float(e[u][1]));
      j += 4;
    }
    for (; j < je; j++){
      i32x2 e = __builtin_nontemporal_load(bce + j);
      uint4 p = *(const uint4*)(H + (size_t)e[0]*D + lane*8);
      acc_bf16(a, p, __int_as_float(e[1]));
    }
    uint4 o;
    o.x = f2bf(a[0]) | (f2bf(a[1]) << 16);
    o.y = f2bf(a[2]) | (f2bf(a[3]) << 16);
    o.z = f2bf(a[4]) | (f2bf(a[5]) << 16);
    o.w = f2bf(a[6]) | (f2bf(a[7]) << 16);
    *(uint4*)(out + (size_t)row*D + lane*8) = o;
  }
}

// ---------------- bf16 MFMA GEMM: C[M,512] = A[M,512] @ B[512,512]^T + bias ----------------
__device__ __forceinline__ void gload16(const unsigned short* g, unsigned short* l){
  __builtin_amdgcn_global_load_lds(
      (const __attribute__((address_space(1))) unsigned int*)(const void*)g,
      (__attribute__((address_space(3))) unsigned int*)(void*)l,
      16, 0, 0);
}

template<bool OUT_BF16>
__global__ __launch_bounds__(256) void k_gemm_bias(
    const unsigned short* __restrict__ A,
    const unsigned short* __restrict__ B,
    const float* __restrict__ bias,
    void* __restrict__ Cv,
    int M)
{
  __shared__ unsigned short Al[128*32];
  __shared__ unsigned short Bl[128*32];
  int bx = blockIdx.x & 3, by = blockIdx.x >> 2;
  int m0 = by << 7, n0 = bx << 7;
  int t = threadIdx.x, wave = t >> 6, lane = t & 63;
  int wr = wave >> 1, wc = wave & 1;
  f32x4 acc[4][4] = {};
  int flat = t << 3;
  int r0 = flat >> 5, cc = flat & 31;
  const unsigned short* pa = A + (size_t)(m0 + r0)*D + cc;
  const unsigned short* pb = B + (size_t)(n0 + r0)*D + cc;
  for (int k0 = 0; k0 < D; k0 += 32){
    gload16(pa + k0,                 &Al[flat]);
    gload16(pa + (size_t)64*D + k0,  &Al[flat + 2048]);
    gload16(pb + k0,                 &Bl[flat]);
    gload16(pb + (size_t)64*D + k0,  &Bl[flat + 2048]);
    __syncthreads();
    int arow = (wr << 6) | (lane & 15);
    int brow = (wc << 6) | (lane & 15);
    int kg   = (lane >> 4) << 3;
    bf16x8 af[4], bfr[4];
    #pragma unroll
    for (int mi=0; mi<4; mi++) af[mi]  = *(const bf16x8*)&Al[(arow + (mi<<4))*32 + kg];
    #pragma unroll
    for (int ni=0; ni<4; ni++) bfr[ni] = *(const bf16x8*)&Bl[(brow + (ni<<4))*32 + kg];
    #pragma unroll
    for (int mi=0; mi<4; mi++)
      #pragma unroll
      for (int ni=0; ni<4; ni++)
        acc[mi][ni] = __builtin_amdgcn_mfma_f32_16x16x32_bf16(af[mi], bfr[ni], acc[mi][ni], 0, 0, 0);
    __syncthreads();
  }
  int crow = m0 + (wr << 6) + ((lane >> 4) << 2);
  int ccol = n0 + (wc << 6) + (lane & 15);
  #pragma unroll
  for (int mi=0; mi<4; mi++){
    #pragma unroll
    for (int q=0; q<4; q++){
      int row = crow + (mi << 4) + q;
      #pragma unroll
      for (int ni=0; ni<4; ni++){
        float val = acc[mi][ni][q] + bias[ccol + (ni << 4)];
        if (OUT_BF16)
          ((unsigned short*)Cv)[(size_t)row*D + ccol + (ni << 4)] = (unsigned short)f2bf(val);
        else
          ((float*)Cv)[(size_t)row*D + ccol + (ni << 4)] = val;
      }
    }
  }
}

// ---------------- LayerNorm + ReLU + subtract hist1[sid1] -> bf16 (y in bf16) ----------------
__global__ __launch_bounds__(256) void k_ln_relu_sub(
    const unsigned short* __restrict__ y, const float* __restrict__ gam, const float* __restrict__ bet,
    const float* __restrict__ hist1, const int* __restrict__ sid1,
    unsigned short* __restrict__ out)
{
  __shared__ float sh[8];
  int row = blockIdx.x, t = threadIdx.x;
  int c = t << 1;
  unsigned pv = *(const unsigned*)(y + (size_t)row*D + c);
  float vx = bf2f(pv & 0xffffu), vy = bf2f(pv >> 16);
  float s = vx + vy, ss = vx*vx + vy*vy;
  #pragma unroll
  for (int m=1; m<64; m<<=1){ s += __shfl_xor(s, m); ss += __shfl_xor(ss, m); }
  int wave = t >> 6, lane = t & 63;
  if (lane == 0){ sh[wave] = s; sh[4+wave] = ss; }
  __syncthreads();
  s  = sh[0]+sh[1]+sh[2]+sh[3];
  ss = sh[4]+sh[5]+sh[6]+sh[7];
  float mu  = s * (1.f/D);
  float var = ss * (1.f/D) - mu*mu;
  float rr  = rsqrtf(var + 1e-5f);
  int srow = sid1[row];
  float2 hv = *(const float2*)(hist1 + (size_t)srow*D + c);
  float o0 = fmaxf((vx - mu)*rr*gam[c]   + bet[c],   0.f) - hv.x;
  float o1 = fmaxf((vy - mu)*rr*gam[c+1] + bet[c+1], 0.f) - hv.y;
  *(unsigned*)(out + (size_t)row*D + c) = f2bf(o0) | (f2bf(o1) << 16);
}

// ---------------- log_softmax rows ----------------
__global__ __launch_bounds__(256) void k_logsoftmax(const float* __restrict__ y, float* __restrict__ out){
  __shared__ float sh[8];
  int row = blockIdx.x, t = threadIdx.x;
  int c = t << 1;
  float2 v = *(const float2*)(y + (size_t)row*D + c);
  float m = fmaxf(v.x, v.y);
  #pragma unroll
  for (int k=1; k<64; k<<=1) m = fmaxf(m, __shfl_xor(m, k));
  int wave = t >> 6, lane = t & 63;
  if (lane == 0) sh[wave] = m;
  __syncthreads();
  m = fmaxf(fmaxf(sh[0], sh[1]), fmaxf(sh[2], sh[3]));
  __syncthreads();
  float e = expf(v.x - m) + expf(v.y - m);
  #pragma unroll
  for (int k=1; k<64; k<<=1) e += __shfl_xor(e, k);
  if (lane == 0) sh[4+wave] = e;
  __syncthreads();
  e = sh[4]+sh[5]+sh[6]+sh[7];
  float lse = m + logf(e);
  float2 o; o.x = v.x - lse; o.y = v.y - lse;
  *(float2*)(out + (size_t)row*D + c) = o;
}

extern "C" void kernel_launch(void* const* d_in, const int* in_sizes, int n_in,
                              void* d_out, int out_size, void* d_ws, size_t ws_size,
                              hipStream_t stream)
{
  const float* x     = (const float*)d_in[0];
  const float* hist0 = (const float*)d_in[1];
  const float* hist1 = (const float*)d_in[2];
  const float* w0    = (const float*)d_in[3];
  const float* b0    = (const float*)d_in[4];
  const float* g0    = (const float*)d_in[5];
  const float* beta0 = (const float*)d_in[6];
  const float* w1    = (const float*)d_in[7];
  const float* b1    = (const float*)d_in[8];
  const float* s0v   = (const float*)d_in[9];
  const float* s1v   = (const float*)d_in[10];
  const float* f0v   = (const float*)d_in[11];
  const float* f1v   = (const float*)d_in[12];
  const int* sid0    = (const int*)d_in[13];
  const int* sid1    = (const int*)d_in[14];
  const int* fid0    = (const int*)d_in[16];
  const int* fid1    = (const int*)d_in[17];
  const int* s0r     = (const int*)d_in[18];
  const int* s0c     = (const int*)d_in[19];
  const int* s1r     = (const int*)d_in[20];
  const int* s1c     = (const int*)d_in[21];
  const int* f0r     = (const int*)d_in[22];
  const int* f0c     = (const int*)d_in[23];
  const int* f1r     = (const int*)d_in[24];
  const int* f1c     = (const int*)d_in[25];

  const int N1 = 32768, N2 = 8192;
  const int Es0 = 262144, Es1 = 65536, Ef0 = 1048576, Ef1 = 262144;
  const int E0 = 2*Es0 + Ef0;          // merged layer-0 entries
  const int E1 = Es1 + Ef1;            // merged layer-1 entries

  char* ws = (char*)d_ws;
  size_t off = 0;
  auto alloc = [&](size_t bytes)->char*{
    char* p = ws + off; off += (bytes + 255) & ~(size_t)255; return p;
  };
  // T0 = [Xb | H0b] contiguous bf16 table (2*NTAB rows); dead after spmm0 -> y1/y2 reuse
  char* T0 = alloc((size_t)2*NTAB*D*2);          // 204.8 MB
  // T1 = [g1buf | h1] contiguous bf16 table (2*N1 rows)
  char* T1 = alloc((size_t)2*N1*D*2);            // 67.1 MB
  char* regC = alloc((size_t)N1*D*2);            // out1 -> out2 (33.6 MB)
  unsigned short* w0b = (unsigned short*)alloc((size_t)D*D*2);
  unsigned short* w1b = (unsigned short*)alloc((size_t)D*D*2);
  int* meta = (int*)alloc((size_t)(2*N1 + 2*N2)*4);
  int* cnt0 = meta;          int* fill0 = cnt0 + N1;
  int* cnt1 = fill0 + N1;    int* fill1 = cnt1 + N2;
  size_t metaBytes = (size_t)(2*N1 + 2*N2)*4;
  int* rp0 = (int*)alloc((size_t)(N1+1)*4);
  int* rp1 = (int*)alloc((size_t)(N2+1)*4);
  i32x2* bce0 = (i32x2*)alloc((size_t)E0*8);     // 12.6 MB
  i32x2* bce1 = (i32x2*)alloc((size_t)E1*8);     // 2.6 MB

  unsigned short* Xb    = (unsigned short*)T0;
  unsigned short* H0b   = (unsigned short*)(T0 + (size_t)NTAB*D*2);
  unsigned short* g1buf = (unsigned short*)T1;
  unsigned short* h1    = (unsigned short*)(T1 + (size_t)N1*D*2);
  unsigned short* out1  = (unsigned short*)regC;
  unsigned short* out2  = (unsigned short*)regC;             // after gemm0 (out1 dead)
  unsigned short* y1    = (unsigned short*)T0;               // after spmm0 (T0 dead)
  float*          y2    = (float*)(T0 + ((size_t)48<<20));
  float*          outp  = (float*)d_out;

  hipMemsetAsync(meta, 0, metaBytes, stream);
  k_f2bw<<<(2*D*D + 255)/256, 256, 0, stream>>>(w0, w1, w0b, w1b);
  // merged CSR build
  const int Etot = Es0 + Ef0 + Es1 + Ef1;
  k_count2<<<(Etot + 255)/256, 256, 0, stream>>>(s0r, Es0, f0r, Ef0, cnt0,
                                                 s1r, Es1, f1r, Ef1, cnt1);
  k_exscan2<<<2, 1024, 0, stream>>>(cnt0, rp0, N1, cnt1, rp1, N2);
  k_fill2<<<(Etot + 255)/256, 256, 0, stream>>>(
      s0r, s0c, s0v, Es0, f0r, f0c, f0v, Ef0, sid0, fid0, rp0, fill0, bce0,
      s1r, s1c, s1v, Es1, f1r, f1c, f1v, Ef1, rp1, fill1, bce1, N1);
  // tables: x -> Xb, hist0 -> H0b (contiguous)
  k_f2b8<<<(NTAB*D/8 + 255)/256, 256, 0, stream>>>(x,     Xb,  NTAB*D/8);
  k_f2b8<<<(NTAB*D/8 + 255)/256, 256, 0, stream>>>(hist0, H0b, NTAB*D/8);
  // layer 0 aggregation: single uniform merged SpMM
  k_spmm<<<2048, 256, 0, stream>>>(rp0, bce0, Xb, out1, N1);
  // layer-1 history pre-gather
  k_gather1_bf16<<<N1*128/256, 256, 0, stream>>>(hist1, fid1, g1buf, N1);
  // dense + norm (y1 stored bf16; T0 dead after spmm0)
  k_gemm_bias<true><<<(N1/128)*4, 256, 0, stream>>>(out1, w0b, b0, (void*)y1, N1);
  k_ln_relu_sub<<<N1, 256, 0, stream>>>(y1, g0, beta0, hist1, sid1, h1);
  // layer 1 aggregation (table = [g1buf | h1])
  k_spmm<<<2048, 256, 0, stream>>>(rp1, bce1, g1buf, out2, N2);
  // dense + log-softmax (y2 f32)
  k_gemm_bias<false><<<(N2/128)*4, 256, 0, stream>>>(out2, w1b, b1, (void*)y2, N2);
  k_logsoftmax<<<N2, 256, 0, stream>>>(y2, outp);
}